// Round 4
// baseline (11.799 us; speedup 1.0000x reference)
//
#include <hip/hip_runtime.h>
#include <math.h>

#define N_STATE 32

typedef _Float16 f16;
typedef f16 f16x8 __attribute__((ext_vector_type(8)));
typedef float f32x4 __attribute__((ext_vector_type(4)));

// Swizzled byte offset inside a [64 rows][64 f16] table (128 B rows).
// XOR of (row&7) into byte bits 4-6 spreads column-slice ds_read_b128s
// (fixed k, varying row) across banks. Same function on write & read
// (rule #21). XOR touches bits 4-6 only -> 8B/16B units stay contiguous.
__device__ __forceinline__ unsigned swz(int row, int byte_in_row) {
  return (unsigned)(((row << 7) + byte_in_row) ^ ((row & 7) << 4));
}

// softplus via HW transcendentals: ln(1+e^x) = ln2 * log2(1 + exp2(x*log2e)).
__device__ __forceinline__ float softplus_hw(float x) {
  const float t = __builtin_amdgcn_exp2f(x * 1.4426950408889634f);
  return 0.6931471805599453f * __builtin_amdgcn_logf(1.0f + t);
}

// One block (256 threads = 4 waves) per row d.
//   K[d, 64a+b] = sum_k V'[b,k] U'[k,a]   (V as MFMA-A, U as MFMA-B)
//   V'[b,2n] = Re(z_n^b),  V'[b,2n+1] = -Im(z_n^b)
//   U'[2n,a] = Re(G M^a),  U'[2n+1,a] =  Im(G M^a)
// with z = exp(dt*A), M = z^64, G = Cc*Bc. f16 operands, fp32 accumulate.
// D row = b => each lane's 4 acc regs are 4 consecutive l -> dwordx4 stores.
// Same k-addressing is used for both operand tables, so any consistent
// k-permutation of the HW fragment layout cancels; only the C/D layout
// (col=lane&15, row=4*(lane>>4)+reg, verified m89/m91) must be exact.
__global__ __launch_bounds__(256) void s4d_mfma_kernel(
    const float* __restrict__ log_A_real,  // (D,N)
    const float* __restrict__ A_imag,      // (D,N)
    const float* __restrict__ Bp,          // (D,N,2)
    const float* __restrict__ Cp,          // (D,N,2)
    const float* __restrict__ log_dt,      // (D,)
    float* __restrict__ K,                 // (D,L), L=4096
    int L) {
  const int d = blockIdx.x;
  const int tid = threadIdx.x;

  __shared__ float s_wrl2e[N_STATE], s_wirev[N_STATE];
  __shared__ float s_gr[N_STATE], s_gi[N_STATE];
  __shared__ __align__(16) f16 s_U[64 * 64];  // [a][k] swizzled, 8 KB
  __shared__ __align__(16) f16 s_V[64 * 64];  // [b][k] swizzled, 8 KB

  // Phase 1: per-n row constants (HW softplus; short serial chain).
  if (tid < N_STATE) {
    const int n = tid;
    const int idx = d * N_STATE + n;
    const float dt = softplus_hw(log_dt[d]);
    const float wr = -dt * softplus_hw(log_A_real[idx]);  // dt*A_real < 0
    const float wi = dt * A_imag[idx];                    // dt*A_imag >= 0
    s_wrl2e[n] = wr * 1.4426950408889634f;   // log2-scaled for v_exp_f32
    s_wirev[n] = wi * 0.15915494309189535f;  // revolutions for v_sin/v_cos
    const float br = Bp[2 * idx], bi = Bp[2 * idx + 1];
    const float cr = Cp[2 * idx], ci = Cp[2 * idx + 1];
    s_gr[n] = cr * br - ci * bi;
    s_gi[n] = cr * bi + ci * br;
  }
  __syncthreads();

  // Phase 2: build U (threads 0-127) and V (threads 128-255); 16 evals per
  // thread, written as 8x ds_write_b64 (pairs are byte-contiguous).
  {
    const int uh = tid >> 7;      // 0 -> U table, 1 -> V table
    const int idx = tid & 127;
    const int row = idx & 63;     // a (U) or b (V)
    const int nh = idx >> 6;      // n half: [16*nh, 16*nh+16)
    const float sf = uh ? (float)row : (float)(row * 64);  // z^b vs M^a=z^64a
    char* base = (char*)(uh ? s_V : s_U);
#pragma unroll
    for (int j = 0; j < 16; j += 2) {
      union { unsigned u32[2]; unsigned long long u64; } pk2;
#pragma unroll
      for (int jj = 0; jj < 2; ++jj) {
        const int n = nh * 16 + j + jj;
        const float er = __builtin_amdgcn_exp2f(s_wrl2e[n] * sf);
        const float ph = __builtin_amdgcn_fractf(s_wirev[n] * sf);
        const float cs = __builtin_amdgcn_cosf(ph);  // v_cos: revolutions
        const float sn = __builtin_amdgcn_sinf(ph);
        const float zr = er * cs, zi = er * sn;
        float u0, u1;
        if (uh == 0) {
          u0 = s_gr[n] * zr - s_gi[n] * zi;  // Re(G M^a)
          u1 = s_gr[n] * zi + s_gi[n] * zr;  // +Im(G M^a)
        } else {
          u0 = zr;   //  Re(z^b)
          u1 = -zi;  // -Im(z^b)
        }
        union { f16 h[2]; unsigned u; } pk;
        pk.h[0] = (f16)u0;
        pk.h[1] = (f16)u1;
        pk2.u32[jj] = pk.u;
      }
      *(unsigned long long*)(base + swz(row, (nh * 16 + j) * 4)) = pk2.u64;
    }
  }
  __syncthreads();

  // Phase 3: wave wid owns output rows b in [16*wid, 16*wid+16).
  const int wid = tid >> 6;
  const int lane = tid & 63;
  const int r = lane & 15;   // A row (b) / B col (a) / D col
  const int g = lane >> 4;   // k-group

  f16x8 afrag[2];
#pragma unroll
  for (int kt = 0; kt < 2; ++kt)
    afrag[kt] = *(const f16x8*)((const char*)s_V +
                                swz(16 * wid + r, kt * 64 + g * 16));

  f32x4 acc[4];
#pragma unroll
  for (int nt = 0; nt < 4; ++nt) acc[nt] = (f32x4){0.f, 0.f, 0.f, 0.f};

#pragma unroll
  for (int nt = 0; nt < 4; ++nt) {
#pragma unroll
    for (int kt = 0; kt < 2; ++kt) {
      const f16x8 bfrag = *(const f16x8*)((const char*)s_U +
                                          swz(16 * nt + r, kt * 64 + g * 16));
      acc[nt] = __builtin_amdgcn_mfma_f32_16x16x32_f16(afrag[kt], bfrag,
                                                       acc[nt], 0, 0, 0);
    }
  }

  // Epilogue: D row = b = 16*wid + 4*g + reg, col = a = 16*nt + r.
  // l = 64a + b -> lane's 4 regs are consecutive l: one dwordx4 per nt.
  float* outd = K + (size_t)d * L + 16 * wid + 4 * g;
#pragma unroll
  for (int nt = 0; nt < 4; ++nt) {
    __builtin_nontemporal_store(acc[nt],
                                (f32x4*)(outd + 64 * (16 * nt + r)));
  }
}

extern "C" void kernel_launch(void* const* d_in, const int* in_sizes, int n_in,
                              void* d_out, int out_size, void* d_ws,
                              size_t ws_size, hipStream_t stream) {
  const float* log_A_real = (const float*)d_in[0];
  const float* A_imag = (const float*)d_in[1];
  const float* B = (const float*)d_in[2];
  const float* C = (const float*)d_in[3];
  const float* log_dt = (const float*)d_in[4];
  float* K = (float*)d_out;

  const int D = in_sizes[4];   // 1024
  const int L = out_size / D;  // 4096 (kernel assumes 64x64 factorization)

  dim3 grid(D), block(256);
  hipLaunchKernelGGL(s4d_mfma_kernel, grid, block, 0, stream, log_A_real,
                     A_imag, B, C, log_dt, K, L);
}

// Round 5
// 10.760 us; speedup vs baseline: 1.0966x; 1.0966x over previous
//
#include <hip/hip_runtime.h>
#include <math.h>

#define N_STATE 32

typedef _Float16 f16;
typedef f16 f16x8 __attribute__((ext_vector_type(8)));
typedef float f32x4 __attribute__((ext_vector_type(4)));

// Swizzled byte offset inside a [64 rows][64 f16] table (128 B rows).
// XOR of (row&7) into byte bits 4-6 spreads column-slice ds_read_b128s
// (fixed k, varying row) across banks. Same function on write & read
// (rule #21). XOR touches bits 4-6 only -> 8B/16B units stay contiguous.
__device__ __forceinline__ unsigned swz(int row, int byte_in_row) {
  return (unsigned)(((row << 7) + byte_in_row) ^ ((row & 7) << 4));
}

// Output-staging swizzle on fp32 word index (logical word L = 64*a + b):
// XOR (a&7) into word bits 2-4; keeps float4 quads contiguous, balances
// banks to the b128 structural minimum (8 words/bank) on both sides.
__device__ __forceinline__ unsigned oswz(unsigned word) {
  return word ^ (((word >> 6) & 7u) << 2);
}

// softplus via HW transcendentals: ln(1+e^x) = ln2 * log2(1 + exp2(x*log2e)).
__device__ __forceinline__ float softplus_hw(float x) {
  const float t = __builtin_amdgcn_exp2f(x * 1.4426950408889634f);
  return 0.6931471805599453f * __builtin_amdgcn_logf(1.0f + t);
}

// One block (256 threads = 4 waves) per row d.
//   K[d, 64a+b] = sum_k V'[b,k] U'[k,a]   (V as MFMA-A, U as MFMA-B)
//   V'[b,2n] = Re(z_n^b),  V'[b,2n+1] = -Im(z_n^b)
//   U'[2n,a] = Re(G M^a),  U'[2n+1,a] =  Im(G M^a)
// with z = exp(dt*A), M = z^64, G = Cc*Bc. f16 operands, fp32 accumulate.
// Same k-addressing for both operand tables -> any consistent k-permutation
// of the HW A/B fragment layout cancels; only the C/D layout (col=lane&15,
// row=4*(lane>>4)+reg, verified m89/m91) must be exact.
// Epilogue stages the 64x64 fp32 tile through the (dead) U/V LDS and streams
// it out as four contiguous 4KB spans -> full-line HBM writes, no partial
// sectors (round-1 counters showed 2.9x write amplification without this).
__global__ __launch_bounds__(256) void s4d_mfma_kernel(
    const float* __restrict__ log_A_real,  // (D,N)
    const float* __restrict__ A_imag,      // (D,N)
    const float* __restrict__ Bp,          // (D,N,2)
    const float* __restrict__ Cp,          // (D,N,2)
    const float* __restrict__ log_dt,      // (D,)
    float* __restrict__ K,                 // (D,L), L=4096
    int L) {
  const int d = blockIdx.x;
  const int tid = threadIdx.x;

  __shared__ float s_wrl2e[N_STATE], s_wirev[N_STATE];
  __shared__ float s_gr[N_STATE], s_gi[N_STATE];
  // 16 KB: two 8 KB f16 operand tables; reused as the 64x64 fp32 out-stage.
  __shared__ __align__(16) char s_tab[2][64 * 128];
  f16* s_U = (f16*)s_tab[0];
  f16* s_V = (f16*)s_tab[1];
  float* s_out = (float*)s_tab;

  // Phase 1: per-n row constants (HW softplus; short serial chain).
  if (tid < N_STATE) {
    const int n = tid;
    const int idx = d * N_STATE + n;
    const float dt = softplus_hw(log_dt[d]);
    const float wr = -dt * softplus_hw(log_A_real[idx]);  // dt*A_real < 0
    const float wi = dt * A_imag[idx];                    // dt*A_imag >= 0
    s_wrl2e[n] = wr * 1.4426950408889634f;   // log2-scaled for v_exp_f32
    s_wirev[n] = wi * 0.15915494309189535f;  // revolutions for v_sin/v_cos
    const float br = Bp[2 * idx], bi = Bp[2 * idx + 1];
    const float cr = Cp[2 * idx], ci = Cp[2 * idx + 1];
    s_gr[n] = cr * br - ci * bi;
    s_gi[n] = cr * bi + ci * br;
  }
  __syncthreads();

  // Phase 2: build U (threads 0-127) and V (threads 128-255); 16 evals per
  // thread, written as 8x ds_write_b64 (pairs are byte-contiguous).
  {
    const int uh = tid >> 7;      // 0 -> U table, 1 -> V table
    const int idx = tid & 127;
    const int row = idx & 63;     // a (U) or b (V)
    const int nh = idx >> 6;      // n half: [16*nh, 16*nh+16)
    const float sf = uh ? (float)row : (float)(row * 64);  // z^b vs M^a
    char* base = (char*)(uh ? s_V : s_U);
#pragma unroll
    for (int j = 0; j < 16; j += 2) {
      union { unsigned u32[2]; unsigned long long u64; } pk2;
#pragma unroll
      for (int jj = 0; jj < 2; ++jj) {
        const int n = nh * 16 + j + jj;
        const float er = __builtin_amdgcn_exp2f(s_wrl2e[n] * sf);
        const float ph = __builtin_amdgcn_fractf(s_wirev[n] * sf);
        const float cs = __builtin_amdgcn_cosf(ph);  // v_cos: revolutions
        const float sn = __builtin_amdgcn_sinf(ph);
        const float zr = er * cs, zi = er * sn;
        float u0, u1;
        if (uh == 0) {
          u0 = s_gr[n] * zr - s_gi[n] * zi;  // Re(G M^a)
          u1 = s_gr[n] * zi + s_gi[n] * zr;  // +Im(G M^a)
        } else {
          u0 = zr;   //  Re(z^b)
          u1 = -zi;  // -Im(z^b)
        }
        union { f16 h[2]; unsigned u; } pk;
        pk.h[0] = (f16)u0;
        pk.h[1] = (f16)u1;
        pk2.u32[jj] = pk.u;
      }
      *(unsigned long long*)(base + swz(row, (nh * 16 + j) * 4)) = pk2.u64;
    }
  }
  __syncthreads();

  // Phase 3: wave wid owns output rows b in [16*wid, 16*wid+16).
  const int wid = tid >> 6;
  const int lane = tid & 63;
  const int r = lane & 15;   // A row (b) / B col (a) / D col
  const int g = lane >> 4;   // k-group

  f16x8 afrag[2];
#pragma unroll
  for (int kt = 0; kt < 2; ++kt)
    afrag[kt] = *(const f16x8*)((const char*)s_V +
                                swz(16 * wid + r, kt * 64 + g * 16));

  f32x4 acc[4];
#pragma unroll
  for (int nt = 0; nt < 4; ++nt) acc[nt] = (f32x4){0.f, 0.f, 0.f, 0.f};

#pragma unroll
  for (int nt = 0; nt < 4; ++nt) {
#pragma unroll
    for (int kt = 0; kt < 2; ++kt) {
      const f16x8 bfrag = *(const f16x8*)((const char*)s_U +
                                          swz(16 * nt + r, kt * 64 + g * 16));
      acc[nt] = __builtin_amdgcn_mfma_f32_16x16x32_f16(afrag[kt], bfrag,
                                                       acc[nt], 0, 0, 0);
    }
  }

  // Phase 4: stage D tiles into LDS (operand tables are dead after MFMA).
  // D row = b = 16*wid + 4*g + reg, col = a = 16*nt + r; logical word 64a+b.
  __syncthreads();  // WAR: all waves done reading s_U/s_V
#pragma unroll
  for (int nt = 0; nt < 4; ++nt) {
    const unsigned a = (unsigned)(16 * nt + r);
    const unsigned w = oswz(64u * a + (unsigned)(16 * wid + 4 * g));
    *(f32x4*)(s_out + w) = acc[nt];
  }
  __syncthreads();

  // Phase 5: stream out. Instruction i: block writes floats
  // [1024*i, 1024*i+1024) of this d-row -> 4KB contiguous per instruction,
  // 1KB contiguous per wave -> full-line nontemporal HBM writes.
  float* outd = K + (size_t)d * L;
#pragma unroll
  for (int i = 0; i < 4; ++i) {
    const unsigned f = (unsigned)(256 * i + tid);  // float4 index
    const f32x4 v = *(const f32x4*)(s_out + oswz(4u * f));
    __builtin_nontemporal_store(v, (f32x4*)(outd + 4u * f));
  }
}

extern "C" void kernel_launch(void* const* d_in, const int* in_sizes, int n_in,
                              void* d_out, int out_size, void* d_ws,
                              size_t ws_size, hipStream_t stream) {
  const float* log_A_real = (const float*)d_in[0];
  const float* A_imag = (const float*)d_in[1];
  const float* B = (const float*)d_in[2];
  const float* C = (const float*)d_in[3];
  const float* log_dt = (const float*)d_in[4];
  float* K = (float*)d_out;

  const int D = in_sizes[4];   // 1024
  const int L = out_size / D;  // 4096 (kernel assumes 64x64 factorization)

  dim3 grid(D), block(256);
  hipLaunchKernelGGL(s4d_mfma_kernel, grid, block, 0, stream, log_A_real,
                     A_imag, B, C, log_dt, K, L);
}

// Round 7
// 10.393 us; speedup vs baseline: 1.1353x; 1.0353x over previous
//
#include <hip/hip_runtime.h>
#include <math.h>

#define N_STATE 32

typedef _Float16 f16;
typedef __fp16 fp16x2 __attribute__((ext_vector_type(2)));
typedef f16 f16x8 __attribute__((ext_vector_type(8)));
typedef float f32x4 __attribute__((ext_vector_type(4)));

// Swizzled byte offset inside a [64 rows][64 f16] table (128 B rows).
// XOR of (row&7) into byte bits 4-6 spreads column-slice ds_read_b128s
// (fixed k, varying row) across banks; same function on write & read
// (rule #21). XOR touches bits 4-6 only -> 4B/8B/16B units stay intact.
__device__ __forceinline__ unsigned swz(int row, int byte_in_row) {
  return (unsigned)(((row << 7) + byte_in_row) ^ ((row & 7) << 4));
}

// Output-staging swizzle on fp32 word index (logical word 64*a + b).
__device__ __forceinline__ unsigned oswz(unsigned word) {
  return word ^ (((word >> 6) & 7u) << 2);
}

// softplus via HW transcendentals: ln(1+e^x) = ln2 * log2(1 + exp2(x*log2e)).
__device__ __forceinline__ float softplus_hw(float x) {
  const float t = __builtin_amdgcn_exp2f(x * 1.4426950408889634f);
  return 0.6931471805599453f * __builtin_amdgcn_logf(1.0f + t);
}

// One block (256 threads = 4 waves) per row d.
//   K[d, 64a+b] = sum_k V'[b,k] U'[k,a]   (V as MFMA-A, U as MFMA-B)
//   V'[b,2n] = Re(z_n^b),  V'[b,2n+1] = -Im(z_n^b)
//   U'[2n,a] = Re(G M^a),  U'[2n+1,a] =  Im(G M^a)
// z = exp(dt*A), M = z^64, G = Cc*Bc. f16 operands, fp32 MFMA accumulate.
// Table build: one thread per (table, n, 16-row block); 2 transcendental
// evals (base + step) then 15 EXACT geometric-recurrence complex mults —
// 8x fewer trans-pipe ops than per-entry eval. V tracks the conjugated
// state (q = conj(z^b), step conj(z)) so the stored pair is (Re, -Im).
// Same k-addressing for both operand tables -> any consistent k-permutation
// of the HW A/B fragment layout cancels; only the C/D layout (col=lane&15,
// row=4*(lane>>4)+reg, verified m89/m91) must be exact.
__global__ __launch_bounds__(256) void s4d_mfma_kernel(
    const float* __restrict__ log_A_real,  // (D,N)
    const float* __restrict__ A_imag,      // (D,N)
    const float* __restrict__ Bp,          // (D,N,2)
    const float* __restrict__ Cp,          // (D,N,2)
    const float* __restrict__ log_dt,      // (D,)
    float* __restrict__ K,                 // (D,L), L=4096
    int L) {
  const int d = blockIdx.x;
  const int tid = threadIdx.x;

  // 16 KB: two 8 KB f16 operand tables; reused as the 64x64 fp32 out-stage.
  __shared__ __align__(16) char s_tab[2][64 * 128];
  f16* s_U = (f16*)s_tab[0];
  f16* s_V = (f16*)s_tab[1];
  float* s_out = (float*)s_tab;

  // Phase 1+2 fused: task = (uh, n, rblk). uh=0 -> U table, uh=1 -> V.
  {
    const int uh = tid >> 7;
    const int n = tid & 31;
    const int rblk = (tid >> 5) & 3;  // rows 16*rblk .. 16*rblk+15
    const int idx = d * N_STATE + n;

    const float dt = softplus_hw(log_dt[d]);
    const float wr = -dt * softplus_hw(log_A_real[idx]);  // dt*A_real < 0
    const float wi = dt * A_imag[idx];                    // dt*A_imag >= 0
    const float wrl2e = wr * 1.4426950408889634f;   // for v_exp_f32
    const float wirev = wi * 0.15915494309189535f;  // revolutions

    // base = z^sf0 (V: sf0=16*rblk) or z^(64*a0) (U: sf0=1024*rblk);
    // step m = z (V) or M=z^64 (U).
    const float sf0 = uh ? (float)(16 * rblk) : (float)(1024 * rblk);
    const float sst = uh ? 1.0f : 64.0f;
    const float eb = __builtin_amdgcn_exp2f(wrl2e * sf0);
    const float phb = __builtin_amdgcn_fractf(wirev * sf0);
    float pr = eb * __builtin_amdgcn_cosf(phb);
    float pq = eb * __builtin_amdgcn_sinf(phb);
    const float em = __builtin_amdgcn_exp2f(wrl2e * sst);
    const float phm = __builtin_amdgcn_fractf(wirev * sst);
    float mr = em * __builtin_amdgcn_cosf(phm);
    float mi = em * __builtin_amdgcn_sinf(phm);

    if (uh == 0) {
      // p = G * base, G = Cc*Bc
      const float br = Bp[2 * idx], bi = Bp[2 * idx + 1];
      const float cr = Cp[2 * idx], ci = Cp[2 * idx + 1];
      const float gr = cr * br - ci * bi;
      const float gi = cr * bi + ci * br;
      const float tr = gr * pr - gi * pq;
      pq = gr * pq + gi * pr;
      pr = tr;
    } else {
      // conjugate state & step: stored pair becomes (Re z^b, -Im z^b)
      pq = -pq;
      mi = -mi;
    }

    char* tab = s_tab[uh];
    const int r0 = 16 * rblk;
#pragma unroll
    for (int j = 0; j < 16; ++j) {
      union { fp16x2 v; unsigned u; } pk;
      pk.v = __builtin_amdgcn_cvt_pkrtz(pr, pq);
      *(unsigned*)(tab + swz(r0 + j, 4 * n)) = pk.u;
      const float nr = pr * mr - pq * mi;  // exact geometric step
      pq = pr * mi + pq * mr;
      pr = nr;
    }
  }
  __syncthreads();

  // Phase 3: wave wid owns output rows b in [16*wid, 16*wid+16).
  const int wid = tid >> 6;
  const int lane = tid & 63;
  const int r = lane & 15;   // A row (b) / B col (a) / D col
  const int g = lane >> 4;   // k-group

  f16x8 afrag[2];
#pragma unroll
  for (int kt = 0; kt < 2; ++kt)
    afrag[kt] = *(const f16x8*)((const char*)s_V +
                                swz(16 * wid + r, kt * 64 + g * 16));

  f32x4 acc[4];
#pragma unroll
  for (int nt = 0; nt < 4; ++nt) acc[nt] = (f32x4){0.f, 0.f, 0.f, 0.f};

#pragma unroll
  for (int nt = 0; nt < 4; ++nt) {
#pragma unroll
    for (int kt = 0; kt < 2; ++kt) {
      const f16x8 bfrag = *(const f16x8*)((const char*)s_U +
                                          swz(16 * nt + r, kt * 64 + g * 16));
      acc[nt] = __builtin_amdgcn_mfma_f32_16x16x32_f16(afrag[kt], bfrag,
                                                       acc[nt], 0, 0, 0);
    }
  }

  // Phase 4: stage D tiles into LDS (operand tables dead after MFMA).
  // D row = b = 16*wid + 4*g + reg, col = a = 16*nt + r; word = 64a + b.
  __syncthreads();  // WAR: all waves done reading s_U/s_V
#pragma unroll
  for (int nt = 0; nt < 4; ++nt) {
    const unsigned a = (unsigned)(16 * nt + r);
    const unsigned w = oswz(64u * a + (unsigned)(16 * wid + 4 * g));
    *(f32x4*)(s_out + w) = acc[nt];
  }
  __syncthreads();

  // Phase 5: stream out; 4KB contiguous per instruction across the block ->
  // full-line nontemporal HBM writes.
  float* outd = K + (size_t)d * L;
#pragma unroll
  for (int i = 0; i < 4; ++i) {
    const unsigned f = (unsigned)(256 * i + tid);  // float4 index
    const f32x4 v = *(const f32x4*)(s_out + oswz(4u * f));
    __builtin_nontemporal_store(v, (f32x4*)(outd + 4u * f));
  }
}

extern "C" void kernel_launch(void* const* d_in, const int* in_sizes, int n_in,
                              void* d_out, int out_size, void* d_ws,
                              size_t ws_size, hipStream_t stream) {
  const float* log_A_real = (const float*)d_in[0];
  const float* A_imag = (const float*)d_in[1];
  const float* B = (const float*)d_in[2];
  const float* C = (const float*)d_in[3];
  const float* log_dt = (const float*)d_in[4];
  float* K = (float*)d_out;

  const int D = in_sizes[4];   // 1024
  const int L = out_size / D;  // 4096 (kernel assumes 64x64 factorization)

  dim3 grid(D), block(256);
  hipLaunchKernelGGL(s4d_mfma_kernel, grid, block, 0, stream, log_A_real,
                     A_imag, B, C, log_dt, K, L);
}